// Round 2
// 494.512 us; speedup vs baseline: 1.0831x; 1.0831x over previous
//
#include <hip/hip_runtime.h>
#include <cstdint>
#include <cstddef>

#define HH 12
#define DHD 64
#define BB 64
#define SS 512
#define DD 768
#define PP 256
#define N3 2304

typedef __attribute__((ext_vector_type(8))) short bf16x8_t;
typedef __attribute__((ext_vector_type(4))) float f32x4_t;

__constant__ float c_slopes[12] = {
  0.5f, 0.25f, 0.125f, 0.0625f, 0.03125f, 0.015625f, 0.0078125f, 0.00390625f,
  0.70710678118654752f, 0.35355339059327376f, 0.17677669529663688f, 0.08838834764831844f
};

__device__ __forceinline__ ushort f2bf(float f) {
  union { float f; unsigned u; } v; v.f = f;
  unsigned r = v.u + 0x7fffu + ((v.u >> 16) & 1u);  // RNE
  return (ushort)(r >> 16);
}
__device__ __forceinline__ float bf2f(ushort u) {
  union { unsigned u; float f; } v; v.u = ((unsigned)u) << 16;
  return v.f;
}
__device__ __forceinline__ void gload_lds16(const ushort* g, ushort* l) {
  __builtin_amdgcn_global_load_lds(
      (const __attribute__((address_space(1))) void*)g,
      (__attribute__((address_space(3))) void*)l, 16, 0, 0);
}

// ---------------- cast hidden_states fp32 -> bf16 ----------------
__global__ void cast_hs_kernel(const float* __restrict__ in, ushort* __restrict__ out) {
  int i = blockIdx.x * 256 + threadIdx.x;          // exactly 6291456 float4 groups
  float4 v = ((const float4*)in)[i];
  ushort4 o;
  o.x = f2bf(v.x); o.y = f2bf(v.y); o.z = f2bf(v.z); o.w = f2bf(v.w);
  ((ushort4*)out)[i] = o;
}

// ---------------- transpose + cast W (768x2304) -> Wt bf16 (2304x768) ----------------
__global__ void transpose_w_kernel(const float* __restrict__ W, ushort* __restrict__ Wt) {
  __shared__ float tile[32][33];
  int n0 = blockIdx.x * 32, k0 = blockIdx.y * 32;
  int tx = threadIdx.x & 31, ty = threadIdx.x >> 5;
  for (int r = ty; r < 32; r += 8) tile[r][tx] = W[(size_t)(k0 + r) * N3 + n0 + tx];
  __syncthreads();
  for (int r = ty; r < 32; r += 8) Wt[(size_t)(n0 + r) * DD + k0 + tx] = f2bf(tile[tx][r]);
}

// ---------------- GEMM: 256x256 tile, BK=64, 8-phase counted-vmcnt schedule ----------------
// qkv = (A.W + bias) * mask, bf16 out.  A: 32768x768 bf16, Wt: 2304x768 bf16 (N-major).
//
// LDS: As/Bs 2 buffers x 256x64 bf16 (32KB each) = 128KB. Linear staging via
// global_load_lds (dest = wave-uniform base + lane*16); swizzle is applied by
// permuting the GLOBAL source column-group (colgrp = (tid&7) ^ (row&7)) so that
// the LDS holds col-group g of row r at LDS col-group g ^ (r&7). Fragment reads XOR
// ((row&7)<<4) bytes into the offset -> 2-way bank aliasing (free) instead of 8/16-way.
//
// Pipeline (per K-tile t, buffers alternate t&1; prefetch depth = 2 tiles):
//   ph0: read A(m-half0)+B(n-half0) | bar | mfma m0xn0 | bar
//   ph1: read B(n-half1)            | bar | mfma m0xn1 | bar
//   ph2: read A(m-half1)            | bar | STAGE(tile t+2 -> buf t&1) ; mfma m1xn0 | bar
//   ph3:                                    mfma m1xn1 ; vmcnt(8) | bar
// STAGE is issued after the barrier that follows the LAST read of buf[t&1]
// (all reads of the buffer happen in ph0..ph2 read sections) -> no overwrite race.
// vmcnt(8) retires tile t+1's 8 loads (in-order retirement), leaves tile t+2's
// 8 in flight -> counted, never drains to 0 until the 2-iteration tail.
// Raw s_barrier (NOT __syncthreads: that re-inserts the vmcnt(0) drain).
__global__ __launch_bounds__(512, 2) void gemm_qkv_kernel(
    const ushort* __restrict__ A, const ushort* __restrict__ Wt,
    const float* __restrict__ bias, const int* __restrict__ mask,
    ushort* __restrict__ qkv) {
  __shared__ __align__(16) ushort As[2][16384];
  __shared__ __align__(16) ushort Bs[2][16384];
  // XCD-aware swizzle: 1152 blocks, 1152%8==0 -> bijective. bn fastest within an
  // XCD chunk of 144 -> 16 A-panels x 9 bn share A rows in that XCD's L2.
  const int wg = blockIdx.x;
  const int swz = (wg & 7) * 144 + (wg >> 3);
  const int bm = (swz / 9) * 256;
  const int bn = (swz % 9) * 256;
  const int tid = threadIdx.x;
  const int lane = tid & 63;
  const int wave = tid >> 6;
  const int wm = (wave >> 2) * 128;       // 2 M-halves
  const int wn = (wave & 3) * 64;         // 4 N-quarters
  const int fr = lane & 15, quad = lane >> 4;
  const int xr = (fr & 7) << 3;           // swizzle XOR in ushort units
  const int q8 = quad * 8;

  // staging addressing: load l covers rows l*64 + (tid>>3), inverse-swizzled col group
  const int rsub = tid >> 3;
  const int cg8 = ((tid & 7) ^ (rsub & 7)) * 8;
  const ushort* Ag = A  + (size_t)(bm + rsub) * DD + cg8;
  const ushort* Bg = Wt + (size_t)(bn + rsub) * DD + cg8;
  ushort* AsW = &As[0][0] + wave * 512;
  ushort* BsW = &Bs[0][0] + wave * 512;

  f32x4_t acc[8][4];
#pragma unroll
  for (int i = 0; i < 8; i++)
#pragma unroll
    for (int j = 0; j < 4; j++) acc[i][j] = (f32x4_t){0.f, 0.f, 0.f, 0.f};

  // prologue: stage tile 0 -> buf0, tile 1 -> buf1 (16 loads), wait for tile 0 only
#pragma unroll
  for (int l = 0; l < 4; l++) {
    gload_lds16(Ag + (size_t)l * 64 * DD,      AsW + l * 4096);
    gload_lds16(Bg + (size_t)l * 64 * DD,      BsW + l * 4096);
  }
#pragma unroll
  for (int l = 0; l < 4; l++) {
    gload_lds16(Ag + (size_t)l * 64 * DD + 64, AsW + 16384 + l * 4096);
    gload_lds16(Bg + (size_t)l * 64 * DD + 64, BsW + 16384 + l * 4096);
  }
  asm volatile("s_waitcnt vmcnt(8)" ::: "memory");
  __builtin_amdgcn_s_barrier();

#pragma unroll 2
  for (int t = 0; t < 12; t++) {
    const ushort* Ab = &As[t & 1][0];
    const ushort* Bb = &Bs[t & 1][0];
    bf16x8_t a[4][2], b0[2][2], b1[2][2];
    // ---- ph0: read A m-half0 (8) + B n-half0 (4) ----
#pragma unroll
    for (int m = 0; m < 4; m++)
#pragma unroll
      for (int kk = 0; kk < 2; kk++)
        a[m][kk] = *(const bf16x8_t*)&Ab[(wm + m * 16 + fr) * 64 + ((kk * 32 + q8) ^ xr)];
#pragma unroll
    for (int n = 0; n < 2; n++)
#pragma unroll
      for (int kk = 0; kk < 2; kk++)
        b0[n][kk] = *(const bf16x8_t*)&Bb[(wn + n * 16 + fr) * 64 + ((kk * 32 + q8) ^ xr)];
    asm volatile("" ::: "memory");
    __builtin_amdgcn_s_barrier();
    __builtin_amdgcn_s_setprio(1);
#pragma unroll
    for (int m = 0; m < 4; m++)
#pragma unroll
      for (int n = 0; n < 2; n++) {
        acc[m][n] = __builtin_amdgcn_mfma_f32_16x16x32_bf16(a[m][0], b0[n][0], acc[m][n], 0, 0, 0);
        acc[m][n] = __builtin_amdgcn_mfma_f32_16x16x32_bf16(a[m][1], b0[n][1], acc[m][n], 0, 0, 0);
      }
    __builtin_amdgcn_s_setprio(0);
    __builtin_amdgcn_s_barrier();
    // ---- ph1: read B n-half1 (4) ----
#pragma unroll
    for (int n = 0; n < 2; n++)
#pragma unroll
      for (int kk = 0; kk < 2; kk++)
        b1[n][kk] = *(const bf16x8_t*)&Bb[(wn + 32 + n * 16 + fr) * 64 + ((kk * 32 + q8) ^ xr)];
    asm volatile("" ::: "memory");
    __builtin_amdgcn_s_barrier();
    __builtin_amdgcn_s_setprio(1);
#pragma unroll
    for (int m = 0; m < 4; m++)
#pragma unroll
      for (int n = 0; n < 2; n++) {
        acc[m][2 + n] = __builtin_amdgcn_mfma_f32_16x16x32_bf16(a[m][0], b1[n][0], acc[m][2 + n], 0, 0, 0);
        acc[m][2 + n] = __builtin_amdgcn_mfma_f32_16x16x32_bf16(a[m][1], b1[n][1], acc[m][2 + n], 0, 0, 0);
      }
    __builtin_amdgcn_s_setprio(0);
    __builtin_amdgcn_s_barrier();
    // ---- ph2: read A m-half1 (8); then stage tile t+2 into buf[t&1] ----
#pragma unroll
    for (int m = 0; m < 4; m++)
#pragma unroll
      for (int kk = 0; kk < 2; kk++)
        a[m][kk] = *(const bf16x8_t*)&Ab[(wm + 64 + m * 16 + fr) * 64 + ((kk * 32 + q8) ^ xr)];
    asm volatile("" ::: "memory");
    __builtin_amdgcn_s_barrier();
    asm volatile("" ::: "memory");   // pin stage issue below the barrier
    if (t < 10) {
      const size_t koff = (size_t)(t + 2) * 64;
      ushort* Ad = AsW + (t & 1) * 16384;
      ushort* Bd = BsW + (t & 1) * 16384;
#pragma unroll
      for (int l = 0; l < 4; l++) {
        gload_lds16(Ag + (size_t)l * 64 * DD + koff, Ad + l * 4096);
        gload_lds16(Bg + (size_t)l * 64 * DD + koff, Bd + l * 4096);
      }
    }
    __builtin_amdgcn_s_setprio(1);
#pragma unroll
    for (int m = 0; m < 4; m++)
#pragma unroll
      for (int n = 0; n < 2; n++) {
        acc[4 + m][n] = __builtin_amdgcn_mfma_f32_16x16x32_bf16(a[m][0], b0[n][0], acc[4 + m][n], 0, 0, 0);
        acc[4 + m][n] = __builtin_amdgcn_mfma_f32_16x16x32_bf16(a[m][1], b0[n][1], acc[4 + m][n], 0, 0, 0);
      }
    __builtin_amdgcn_s_setprio(0);
    __builtin_amdgcn_s_barrier();
    // ---- ph3: pure MFMA; counted vmcnt retires tile t+1 ----
    __builtin_amdgcn_s_setprio(1);
#pragma unroll
    for (int m = 0; m < 4; m++)
#pragma unroll
      for (int n = 0; n < 2; n++) {
        acc[4 + m][2 + n] = __builtin_amdgcn_mfma_f32_16x16x32_bf16(a[m][0], b1[n][0], acc[4 + m][2 + n], 0, 0, 0);
        acc[4 + m][2 + n] = __builtin_amdgcn_mfma_f32_16x16x32_bf16(a[m][1], b1[n][1], acc[4 + m][2 + n], 0, 0, 0);
      }
    __builtin_amdgcn_s_setprio(0);
    if (t < 10) { asm volatile("s_waitcnt vmcnt(8)" ::: "memory"); }
    else        { asm volatile("s_waitcnt vmcnt(0)" ::: "memory"); }
    __builtin_amdgcn_s_barrier();
  }

  // ---- epilogue: (acc + bias) * mask -> bf16 ----
  float bb[4];
#pragma unroll
  for (int j = 0; j < 4; j++) bb[j] = bias[bn + wn + j * 16 + fr];
#pragma unroll
  for (int i = 0; i < 8; i++) {
    const int gm = bm + wm + i * 16 + quad * 4;
#pragma unroll
    for (int r = 0; r < 4; r++) {
      const float mv = (float)mask[gm + r];
      ushort* orow = qkv + (size_t)(gm + r) * N3 + bn + wn + fr;
#pragma unroll
      for (int j = 0; j < 4; j++)
        orow[j * 16] = f2bf((acc[i][j][r] + bb[j]) * mv);
    }
  }
}

// ---------------- pool: q_pooled, residual, new_mask ----------------
__global__ void pool_kernel(const ushort* __restrict__ qkv, const int* __restrict__ mask,
                            float* __restrict__ out, ushort* __restrict__ qp) {
  int idx = blockIdx.x * 256 + threadIdx.x;       // 64*256*192 total
  int d4 = idx % 192;
  int bp = idx / 192;
  int b = bp >> 8, p = bp & 255;
  int m0 = mask[b*512 + 2*p], m1 = mask[b*512 + 2*p + 1];
  int ms = m0 + m1;
  float inv = 1.0f / (float)(ms < 1 ? 1 : ms);
  const ushort* r0 = qkv + (size_t)(b*512 + 2*p) * N3 + d4*4;
  ushort4 x0 = *(const ushort4*)r0;
  ushort4 x1 = *(const ushort4*)(r0 + N3);
  float y0 = (bf2f(x0.x) + bf2f(x1.x)) * inv;
  float y1 = (bf2f(x0.y) + bf2f(x1.y)) * inv;
  float y2 = (bf2f(x0.z) + bf2f(x1.z)) * inv;
  float y3 = (bf2f(x0.w) + bf2f(x1.w)) * inv;
  float4 y = {y0, y1, y2, y3};
  *(float4*)(out + 12599296 + (size_t)bp * 768 + d4*4) = y;    // residual_query (==0 when masked)
  ushort4 q8;                                                   // fold 1/sqrt(DH)=1/8 into bf16 q
  q8.x = f2bf(y0 * 0.125f); q8.y = f2bf(y1 * 0.125f);
  q8.z = f2bf(y2 * 0.125f); q8.w = f2bf(y3 * 0.125f);
  *(ushort4*)(qp + (size_t)bp * 768 + d4*4) = q8;
  if (d4 == 0) out[12582912 + bp] = (ms > 0) ? 1.0f : 0.0f;     // new_mask
}

// ---------------- attention: per (p-tile 16, h, b) ----------------
__global__ __launch_bounds__(256) void attn_kernel(
    const ushort* __restrict__ qkv, const ushort* __restrict__ qp,
    const int* __restrict__ mask, const float* __restrict__ nmask,
    float* __restrict__ outA) {
  __shared__ __align__(16) ushort q_lds[16][72];
  __shared__ __align__(16) float  sc[16][520];       // later aliased as bf16 P rows
  __shared__ __align__(16) ushort k_st[4][16][72];   // per-wave K staging
  __shared__ __align__(16) ushort vt_st[4][16][40];  // per-wave V^T staging
  const int pt = blockIdx.x, h = blockIdx.y, b = blockIdx.z;
  const int pbase = pt * 16;
  const int tid = threadIdx.x, wave = tid >> 6, lane = tid & 63;
  const int fr = lane & 15, quad = lane >> 4;
  if (tid < 128) {                       // 16 rows x 64 cols, 8 cols per thread
    int r = tid >> 3, cseg = (tid & 7) * 8;
    *(float4*)&q_lds[r][cseg] =
        *(const float4*)(qp + (size_t)(b*256 + pbase + r) * 768 + h*64 + cseg);
  }
  __syncthreads();
  bf16x8_t a0 = *(const bf16x8_t*)&q_lds[fr][quad*8];
  bf16x8_t a1 = *(const bf16x8_t*)&q_lds[fr][32 + quad*8];
  // ---- QK^T: wave handles s in [wave*128, wave*128+128), prefetched pipeline ----
  const ushort* Kb = qkv + (size_t)(b*512) * N3 + 768 + h*64;
  const int kr = lane >> 2, kc = (lane & 3) * 16;
  const ushort* Ksrc = Kb + (size_t)(wave*128 + kr) * N3 + kc;
  float4 kcur0 = *(const float4*)(Ksrc);
  float4 kcur1 = *(const float4*)(Ksrc + 8);
  for (int st = 0; st < 8; st++) {
    int sb = wave*128 + st*16;
    float4 knxt0, knxt1;
    if (st < 7) {
      knxt0 = *(const float4*)(Ksrc + (size_t)(st+1)*16*N3);
      knxt1 = *(const float4*)(Ksrc + (size_t)(st+1)*16*N3 + 8);
    }
    *(float4*)&k_st[wave][kr][kc]     = kcur0;
    *(float4*)&k_st[wave][kr][kc + 8] = kcur1;
    bf16x8_t b0 = *(const bf16x8_t*)&k_st[wave][fr][quad*8];
    bf16x8_t b1 = *(const bf16x8_t*)&k_st[wave][fr][32 + quad*8];
    f32x4_t d = (f32x4_t){0.f, 0.f, 0.f, 0.f};
    d = __builtin_amdgcn_mfma_f32_16x16x32_bf16(a0, b0, d, 0, 0, 0);
    d = __builtin_amdgcn_mfma_f32_16x16x32_bf16(a1, b1, d, 0, 0, 0);
    for (int r = 0; r < 4; r++) sc[quad*4 + r][sb + fr] = d[r];
    kcur0 = knxt0; kcur1 = knxt1;
  }
  __syncthreads();
  // ---- softmax + bias (ALiBi + pair mask); P -> bf16 aliased over sc rows ----
  const float slope = c_slopes[h];
  int kvalid[8];
  for (int j = 0; j < 8; j++) kvalid[j] = mask[b*512 + lane + j*64];
  for (int i = 0; i < 4; i++) {
    int r = wave*4 + i;
    int p = pbase + r;
    bool rowv = nmask[b*256 + p] > 0.5f;
    float vals[8];
    float mx = -3.0e38f;
    for (int j = 0; j < 8; j++) {
      int s = lane + j*64;
      float v = sc[r][s];
      v += ((rowv && kvalid[j]) ? 0.0f : -10000.0f) - slope * fabsf((float)(s - p));
      vals[j] = v;
      mx = fmaxf(mx, v);
    }
    for (int off = 32; off > 0; off >>= 1) mx = fmaxf(mx, __shfl_xor(mx, off, 64));
    float sum = 0.f;
    for (int j = 0; j < 8; j++) { vals[j] = __expf(vals[j] - mx); sum += vals[j]; }
    for (int off = 32; off > 0; off >>= 1) sum += __shfl_xor(sum, off, 64);
    float inv = 1.0f / sum;
    ushort* prow = (ushort*)&sc[r][0];
    for (int j = 0; j < 8; j++) prow[lane + j*64] = f2bf(vals[j] * inv);
  }
  __syncthreads();
  // ---- P.V: wave handles d-range [wave*16, wave*16+16), prefetched pipeline ----
  const ushort* Vb = qkv + (size_t)(b*512) * N3 + 1536 + h*64 + wave*16;
  const int vs = lane >> 1, vd8 = (lane & 1) * 8;
  const ushort* Vsrc = Vb + (size_t)vs * N3 + vd8;
  f32x4_t acc = (f32x4_t){0.f, 0.f, 0.f, 0.f};
  float4 vcur = *(const float4*)(Vsrc);
  for (int ks = 0; ks < 16; ks++) {
    int sb = ks * 32;
    float4 vnxt;
    if (ks < 15) vnxt = *(const float4*)(Vsrc + (size_t)(ks+1)*32*N3);
    {
      ushort tmp[8];
      *(float4*)tmp = vcur;
      for (int j = 0; j < 8; j++) vt_st[wave][vd8 + j][vs] = tmp[j];
    }
    const ushort* prow = (const ushort*)&sc[fr][0];
    bf16x8_t ap = *(const bf16x8_t*)&prow[sb + quad*8];
    bf16x8_t bv = *(const bf16x8_t*)&vt_st[wave][fr][quad*8];
    acc = __builtin_amdgcn_mfma_f32_16x16x32_bf16(ap, bv, acc, 0, 0, 0);
    vcur = vnxt;
  }
  for (int r = 0; r < 4; r++) {
    int p = pbase + quad*4 + r;
    float nm = nmask[b*256 + p];
    outA[(size_t)(b*256 + p) * 768 + h*64 + wave*16 + fr] = acc[r] * nm;
  }
}

extern "C" void kernel_launch(void* const* d_in, const int* in_sizes, int n_in,
                              void* d_out, int out_size, void* d_ws, size_t ws_size,
                              hipStream_t stream) {
  const float* hs   = (const float*)d_in[0];
  const int*   mask = (const int*)d_in[1];
  const float* W    = (const float*)d_in[2];
  const float* bias = (const float*)d_in[3];
  float* out = (float*)d_out;
  char* ws = (char*)d_ws;
  // ws layout (bytes): A_bf16 [0, 50331648) ; Wt [50331648, 53870592) ;
  //                    qkv_bf16 [53870592, 204865536). qp aliases A (A dead after GEMM).
  ushort* A   = (ushort*)(ws);
  ushort* Wt  = (ushort*)(ws + 50331648);
  ushort* qkv = (ushort*)(ws + 53870592);
  ushort* qp  = (ushort*)(ws);

  hipLaunchKernelGGL(cast_hs_kernel, dim3(24576), dim3(256), 0, stream, hs, A);
  hipLaunchKernelGGL(transpose_w_kernel, dim3(72, 24), dim3(256), 0, stream, W, Wt);
  hipLaunchKernelGGL(gemm_qkv_kernel, dim3(1152), dim3(512), 0, stream, A, Wt, bias, mask, qkv);
  hipLaunchKernelGGL(pool_kernel, dim3(12288), dim3(256), 0, stream, qkv, mask, out, qp);
  hipLaunchKernelGGL(attn_kernel, dim3(16, 12, 64), dim3(256), 0, stream,
                     qkv, qp, mask, out + 12582912, out);
}

// Round 3
// 416.213 us; speedup vs baseline: 1.2868x; 1.1881x over previous
//
#include <hip/hip_runtime.h>
#include <cstdint>
#include <cstddef>

#define HH 12
#define DHD 64
#define BB 64
#define SS 512
#define DD 768
#define PP 256
#define N3 2304

typedef __attribute__((ext_vector_type(8))) short bf16x8_t;
typedef __attribute__((ext_vector_type(4))) float f32x4_t;

__constant__ float c_slopes[12] = {
  0.5f, 0.25f, 0.125f, 0.0625f, 0.03125f, 0.015625f, 0.0078125f, 0.00390625f,
  0.70710678118654752f, 0.35355339059327376f, 0.17677669529663688f, 0.08838834764831844f
};

__device__ __forceinline__ ushort f2bf(float f) {
  union { float f; unsigned u; } v; v.f = f;
  unsigned r = v.u + 0x7fffu + ((v.u >> 16) & 1u);  // RNE
  return (ushort)(r >> 16);
}
__device__ __forceinline__ float bf2f(ushort u) {
  union { unsigned u; float f; } v; v.u = ((unsigned)u) << 16;
  return v.f;
}
__device__ __forceinline__ void gload_lds16(const ushort* g, ushort* l) {
  __builtin_amdgcn_global_load_lds(
      (const __attribute__((address_space(1))) void*)g,
      (__attribute__((address_space(3))) void*)l, 16, 0, 0);
}

// ---------------- cast hidden_states fp32 -> bf16 ----------------
__global__ void cast_hs_kernel(const float* __restrict__ in, ushort* __restrict__ out) {
  int i = blockIdx.x * 256 + threadIdx.x;          // exactly 6291456 float4 groups
  float4 v = ((const float4*)in)[i];
  ushort4 o;
  o.x = f2bf(v.x); o.y = f2bf(v.y); o.z = f2bf(v.z); o.w = f2bf(v.w);
  ((ushort4*)out)[i] = o;
}

// ---------------- transpose + cast W (768x2304) -> Wt bf16 (2304x768) ----------------
__global__ void transpose_w_kernel(const float* __restrict__ W, ushort* __restrict__ Wt) {
  __shared__ float tile[32][33];
  int n0 = blockIdx.x * 32, k0 = blockIdx.y * 32;
  int tx = threadIdx.x & 31, ty = threadIdx.x >> 5;
  for (int r = ty; r < 32; r += 8) tile[r][tx] = W[(size_t)(k0 + r) * N3 + n0 + tx];
  __syncthreads();
  for (int r = ty; r < 32; r += 8) Wt[(size_t)(n0 + r) * DD + k0 + tx] = f2bf(tile[tx][r]);
}

// ---------------- GEMM: 256x256 tile, BK=64, phase-split counted-vmcnt (unchanged) ----------------
__global__ __launch_bounds__(512, 2) void gemm_qkv_kernel(
    const ushort* __restrict__ A, const ushort* __restrict__ Wt,
    const float* __restrict__ bias, const int* __restrict__ mask,
    ushort* __restrict__ qkv) {
  __shared__ __align__(16) ushort As[2][16384];
  __shared__ __align__(16) ushort Bs[2][16384];
  const int wg = blockIdx.x;
  const int swz = (wg & 7) * 144 + (wg >> 3);
  const int bm = (swz / 9) * 256;
  const int bn = (swz % 9) * 256;
  const int tid = threadIdx.x;
  const int lane = tid & 63;
  const int wave = tid >> 6;
  const int wm = (wave >> 2) * 128;
  const int wn = (wave & 3) * 64;
  const int fr = lane & 15, quad = lane >> 4;
  const int xr = (fr & 7) << 3;
  const int q8 = quad * 8;

  const int rsub = tid >> 3;
  const int cg8 = ((tid & 7) ^ (rsub & 7)) * 8;
  const ushort* Ag = A  + (size_t)(bm + rsub) * DD + cg8;
  const ushort* Bg = Wt + (size_t)(bn + rsub) * DD + cg8;
  ushort* AsW = &As[0][0] + wave * 512;
  ushort* BsW = &Bs[0][0] + wave * 512;

  f32x4_t acc[8][4];
#pragma unroll
  for (int i = 0; i < 8; i++)
#pragma unroll
    for (int j = 0; j < 4; j++) acc[i][j] = (f32x4_t){0.f, 0.f, 0.f, 0.f};

#pragma unroll
  for (int l = 0; l < 4; l++) {
    gload_lds16(Ag + (size_t)l * 64 * DD,      AsW + l * 4096);
    gload_lds16(Bg + (size_t)l * 64 * DD,      BsW + l * 4096);
  }
#pragma unroll
  for (int l = 0; l < 4; l++) {
    gload_lds16(Ag + (size_t)l * 64 * DD + 64, AsW + 16384 + l * 4096);
    gload_lds16(Bg + (size_t)l * 64 * DD + 64, BsW + 16384 + l * 4096);
  }
  asm volatile("s_waitcnt vmcnt(8)" ::: "memory");
  __builtin_amdgcn_s_barrier();

#pragma unroll 2
  for (int t = 0; t < 12; t++) {
    const ushort* Ab = &As[t & 1][0];
    const ushort* Bb = &Bs[t & 1][0];
    bf16x8_t a[4][2], b0[2][2], b1[2][2];
#pragma unroll
    for (int m = 0; m < 4; m++)
#pragma unroll
      for (int kk = 0; kk < 2; kk++)
        a[m][kk] = *(const bf16x8_t*)&Ab[(wm + m * 16 + fr) * 64 + ((kk * 32 + q8) ^ xr)];
#pragma unroll
    for (int n = 0; n < 2; n++)
#pragma unroll
      for (int kk = 0; kk < 2; kk++)
        b0[n][kk] = *(const bf16x8_t*)&Bb[(wn + n * 16 + fr) * 64 + ((kk * 32 + q8) ^ xr)];
    asm volatile("" ::: "memory");
    __builtin_amdgcn_s_barrier();
    __builtin_amdgcn_s_setprio(1);
#pragma unroll
    for (int m = 0; m < 4; m++)
#pragma unroll
      for (int n = 0; n < 2; n++) {
        acc[m][n] = __builtin_amdgcn_mfma_f32_16x16x32_bf16(a[m][0], b0[n][0], acc[m][n], 0, 0, 0);
        acc[m][n] = __builtin_amdgcn_mfma_f32_16x16x32_bf16(a[m][1], b0[n][1], acc[m][n], 0, 0, 0);
      }
    __builtin_amdgcn_s_setprio(0);
    __builtin_amdgcn_s_barrier();
#pragma unroll
    for (int n = 0; n < 2; n++)
#pragma unroll
      for (int kk = 0; kk < 2; kk++)
        b1[n][kk] = *(const bf16x8_t*)&Bb[(wn + 32 + n * 16 + fr) * 64 + ((kk * 32 + q8) ^ xr)];
    asm volatile("" ::: "memory");
    __builtin_amdgcn_s_barrier();
    __builtin_amdgcn_s_setprio(1);
#pragma unroll
    for (int m = 0; m < 4; m++)
#pragma unroll
      for (int n = 0; n < 2; n++) {
        acc[m][2 + n] = __builtin_amdgcn_mfma_f32_16x16x32_bf16(a[m][0], b1[n][0], acc[m][2 + n], 0, 0, 0);
        acc[m][2 + n] = __builtin_amdgcn_mfma_f32_16x16x32_bf16(a[m][1], b1[n][1], acc[m][2 + n], 0, 0, 0);
      }
    __builtin_amdgcn_s_setprio(0);
    __builtin_amdgcn_s_barrier();
#pragma unroll
    for (int m = 0; m < 4; m++)
#pragma unroll
      for (int kk = 0; kk < 2; kk++)
        a[m][kk] = *(const bf16x8_t*)&Ab[(wm + 64 + m * 16 + fr) * 64 + ((kk * 32 + q8) ^ xr)];
    asm volatile("" ::: "memory");
    __builtin_amdgcn_s_barrier();
    asm volatile("" ::: "memory");
    if (t < 10) {
      const size_t koff = (size_t)(t + 2) * 64;
      ushort* Ad = AsW + (t & 1) * 16384;
      ushort* Bd = BsW + (t & 1) * 16384;
#pragma unroll
      for (int l = 0; l < 4; l++) {
        gload_lds16(Ag + (size_t)l * 64 * DD + koff, Ad + l * 4096);
        gload_lds16(Bg + (size_t)l * 64 * DD + koff, Bd + l * 4096);
      }
    }
    __builtin_amdgcn_s_setprio(1);
#pragma unroll
    for (int m = 0; m < 4; m++)
#pragma unroll
      for (int n = 0; n < 2; n++) {
        acc[4 + m][n] = __builtin_amdgcn_mfma_f32_16x16x32_bf16(a[m][0], b0[n][0], acc[4 + m][n], 0, 0, 0);
        acc[4 + m][n] = __builtin_amdgcn_mfma_f32_16x16x32_bf16(a[m][1], b0[n][1], acc[4 + m][n], 0, 0, 0);
      }
    __builtin_amdgcn_s_setprio(0);
    __builtin_amdgcn_s_barrier();
    __builtin_amdgcn_s_setprio(1);
#pragma unroll
    for (int m = 0; m < 4; m++)
#pragma unroll
      for (int n = 0; n < 2; n++) {
        acc[4 + m][2 + n] = __builtin_amdgcn_mfma_f32_16x16x32_bf16(a[m][0], b1[n][0], acc[4 + m][2 + n], 0, 0, 0);
        acc[4 + m][2 + n] = __builtin_amdgcn_mfma_f32_16x16x32_bf16(a[m][1], b1[n][1], acc[4 + m][2 + n], 0, 0, 0);
      }
    __builtin_amdgcn_s_setprio(0);
    if (t < 10) { asm volatile("s_waitcnt vmcnt(8)" ::: "memory"); }
    else        { asm volatile("s_waitcnt vmcnt(0)" ::: "memory"); }
    __builtin_amdgcn_s_barrier();
  }

  float bb[4];
#pragma unroll
  for (int j = 0; j < 4; j++) bb[j] = bias[bn + wn + j * 16 + fr];
#pragma unroll
  for (int i = 0; i < 8; i++) {
    const int gm = bm + wm + i * 16 + quad * 4;
#pragma unroll
    for (int r = 0; r < 4; r++) {
      const float mv = (float)mask[gm + r];
      ushort* orow = qkv + (size_t)(gm + r) * N3 + bn + wn + fr;
#pragma unroll
      for (int j = 0; j < 4; j++)
        orow[j * 16] = f2bf((acc[i][j][r] + bb[j]) * mv);
    }
  }
}

// ---------------- pool: q_pooled, residual, new_mask ----------------
__global__ void pool_kernel(const ushort* __restrict__ qkv, const int* __restrict__ mask,
                            float* __restrict__ out, ushort* __restrict__ qp) {
  int idx = blockIdx.x * 256 + threadIdx.x;       // 64*256*192 total
  int d4 = idx % 192;
  int bp = idx / 192;
  int b = bp >> 8, p = bp & 255;
  int m0 = mask[b*512 + 2*p], m1 = mask[b*512 + 2*p + 1];
  int ms = m0 + m1;
  float inv = 1.0f / (float)(ms < 1 ? 1 : ms);
  const ushort* r0 = qkv + (size_t)(b*512 + 2*p) * N3 + d4*4;
  ushort4 x0 = *(const ushort4*)r0;
  ushort4 x1 = *(const ushort4*)(r0 + N3);
  float y0 = (bf2f(x0.x) + bf2f(x1.x)) * inv;
  float y1 = (bf2f(x0.y) + bf2f(x1.y)) * inv;
  float y2 = (bf2f(x0.z) + bf2f(x1.z)) * inv;
  float y3 = (bf2f(x0.w) + bf2f(x1.w)) * inv;
  float4 y = {y0, y1, y2, y3};
  *(float4*)(out + 12599296 + (size_t)bp * 768 + d4*4) = y;    // residual_query (==0 when masked)
  ushort4 q8;                                                   // fold 1/sqrt(DH)=1/8 into bf16 q
  q8.x = f2bf(y0 * 0.125f); q8.y = f2bf(y1 * 0.125f);
  q8.z = f2bf(y2 * 0.125f); q8.w = f2bf(y3 * 0.125f);
  *(ushort4*)(qp + (size_t)bp * 768 + d4*4) = q8;
  if (d4 == 0) out[12582912 + bp] = (ms > 0) ? 1.0f : 0.0f;     // new_mask
}

// ---------------- attention v2: one block per (h,b), flash-style, LDS-resident K/V^T ------
// 512 threads = 8 waves; wave w owns p-rows [w*32, w*32+32).
// K_lds  [512][64] bf16 (128B rows, XOR-swizzled chunks): staged via global_load_lds with
//   inverse-swizzled GLOBAL source (rule: linear dest + inv-swz source + swz read).
// VT_lds [64][512] bf16 (1024B rows, XOR-swizzled): V transposed once, reg-staged.
// P_lds  per-wave [32][40] bf16 (80B rows -> bank stride 20, 2-way = free).
// Swapped QK^T: mfma(A=K rows s, B=Q rows p) -> S^T tiles (row=s, col=p): softmax row-
//   reduce = 16 in-lane values + shfl_xor(16,32). P^T C-layout packs into b64 LDS writes.
// Row-validity (new_mask) is dropped from the bias: rows with nm=0 are zeroed by the
//   final *nm, matching the reference output exactly.
// One __syncthreads after staging; main loop is barrier-free (P_lds is per-wave).
__global__ __launch_bounds__(512, 2) void attn_kernel(
    const ushort* __restrict__ qkv, const ushort* __restrict__ qp,
    const int* __restrict__ mask, const float* __restrict__ nmask,
    float* __restrict__ outA) {
  __shared__ __align__(16) ushort K_lds[512 * 64];
  __shared__ __align__(16) ushort VT_lds[64 * 512];
  __shared__ __align__(16) ushort P_lds[8][32][40];
  __shared__ __align__(16) float  kb[512];
  const int h = blockIdx.x, b = blockIdx.y;
  const int tid = threadIdx.x, wave = tid >> 6, lane = tid & 63;
  const int fr = lane & 15, quad = lane >> 4;
  const int kxor = (fr & 7) << 4;                 // byte-XOR for swizzled LDS reads
  const float slope = c_slopes[h];

  // ---- stage K (global_load_lds, 8 instrs/wave, rows wave*64..+64) ----
  {
    const int r0 = lane >> 3;
    const int cg = ((lane & 7) ^ r0) * 8;         // inverse-swizzled source chunk
    const ushort* Ks = qkv + (size_t)(b * 512 + wave * 64 + r0) * N3 + 768 + h * 64 + cg;
#pragma unroll
    for (int i = 0; i < 8; i++)
      gload_lds16(Ks + (size_t)i * 8 * N3, K_lds + (wave * 64 + i * 8) * 64);
  }
  // ---- stage V^T (reg-staged, swizzled scalar writes; once per block) ----
  {
    const ushort* Vs = qkv + (size_t)(b * 512 + tid) * N3 + 1536 + h * 64;
    float4 vr[8];
#pragma unroll
    for (int d0 = 0; d0 < 8; d0++) vr[d0] = *(const float4*)(Vs + d0 * 8);
    const int s2 = tid * 2;                       // byte col in VT row
    const int sbase = (s2 & ~15), slo = (s2 & 15);
#pragma unroll
    for (int d0 = 0; d0 < 8; d0++) {
      ushort tmp[8];
      *(float4*)tmp = vr[d0];
#pragma unroll
      for (int j = 0; j < 8; j++) {
        int d = d0 * 8 + j;
        *(ushort*)((char*)VT_lds + (size_t)d * 1024 + ((sbase ^ ((d & 7) << 4)) + slo)) = tmp[j];
      }
    }
  }
  kb[tid] = mask[b * 512 + tid] ? 0.0f : -10000.0f;
  // ---- Q fragments (B-operand rows p, direct from global) ----
  bf16x8_t qf[2][2];
#pragma unroll
  for (int nt = 0; nt < 2; nt++)
#pragma unroll
    for (int ks = 0; ks < 2; ks++)
      qf[nt][ks] = *(const bf16x8_t*)(qp + (size_t)(b * 256 + wave * 32 + nt * 16 + fr) * 768
                                      + h * 64 + ks * 32 + quad * 8);
  __syncthreads();   // drains vmcnt+lgkmcnt: K gload_lds + VT/kb writes all visible

  const char* Kc = (const char*)K_lds;
  const char* Vc = (const char*)VT_lds;
  char* Pw = (char*)&P_lds[wave][0][0];

  f32x4_t O[2][4];
#pragma unroll
  for (int i = 0; i < 2; i++)
#pragma unroll
    for (int j = 0; j < 4; j++) O[i][j] = (f32x4_t){0.f, 0.f, 0.f, 0.f};
  float m_run[2] = {-3.0e38f, -3.0e38f};
  float l_run[2] = {0.f, 0.f};

  for (int sb = 0; sb < 512; sb += 64) {
    // ---- QK^T (swapped): S^T[s][p], 8 LDS reads + 16 MFMA ----
    f32x4_t sacc[4][2];
#pragma unroll
    for (int mt = 0; mt < 4; mt++) { sacc[mt][0] = (f32x4_t){0,0,0,0}; sacc[mt][1] = (f32x4_t){0,0,0,0}; }
#pragma unroll
    for (int ks = 0; ks < 2; ks++)
#pragma unroll
      for (int mt = 0; mt < 4; mt++) {
        bf16x8_t ak = *(const bf16x8_t*)(Kc + (size_t)(sb + mt * 16 + fr) * 128
                                         + ((ks * 64 + quad * 16) ^ kxor));
        sacc[mt][0] = __builtin_amdgcn_mfma_f32_16x16x32_bf16(ak, qf[0][ks], sacc[mt][0], 0, 0, 0);
        sacc[mt][1] = __builtin_amdgcn_mfma_f32_16x16x32_bf16(ak, qf[1][ks], sacc[mt][1], 0, 0, 0);
      }
    // ---- bias + online softmax (per nt = p-half) ----
    float kbv[4][4];
#pragma unroll
    for (int mt = 0; mt < 4; mt++) {
      f32x4_t kv = *(const f32x4_t*)&kb[sb + mt * 16 + quad * 4];
#pragma unroll
      for (int r = 0; r < 4; r++) kbv[mt][r] = kv[r];
    }
    float pv2[2][4][4];
    float fsv[2];
#pragma unroll
    for (int nt = 0; nt < 2; nt++) {
      const float pidx = (float)(wave * 32 + nt * 16 + fr);
      float mx = -3.0e38f;
#pragma unroll
      for (int mt = 0; mt < 4; mt++)
#pragma unroll
        for (int r = 0; r < 4; r++) {
          float s_ = (float)(sb + mt * 16 + quad * 4 + r);
          float v = sacc[mt][nt][r] + kbv[mt][r] - slope * fabsf(s_ - pidx);
          pv2[nt][mt][r] = v;
          mx = fmaxf(mx, v);
        }
      mx = fmaxf(mx, __shfl_xor(mx, 16, 64));
      mx = fmaxf(mx, __shfl_xor(mx, 32, 64));
      float mnew = fmaxf(m_run[nt], mx);
      float f = __expf(m_run[nt] - mnew);
      m_run[nt] = mnew; fsv[nt] = f;
      float rs = 0.f;
#pragma unroll
      for (int mt = 0; mt < 4; mt++)
#pragma unroll
        for (int r = 0; r < 4; r++) {
          float e = __expf(pv2[nt][mt][r] - mnew);
          pv2[nt][mt][r] = e; rs += e;
        }
      rs += __shfl_xor(rs, 16, 64);
      rs += __shfl_xor(rs, 32, 64);
      l_run[nt] = l_run[nt] * f + rs;
    }
    // ---- rescale O (factor redistributed via shfl: row p needs lane quad*4+r) ----
#pragma unroll
    for (int mp = 0; mp < 2; mp++)
#pragma unroll
      for (int r = 0; r < 4; r++) {
        float fb = __shfl(fsv[mp], quad * 4 + r, 64);
#pragma unroll
        for (int nd = 0; nd < 4; nd++) O[mp][nd][r] *= fb;
      }
    // ---- PV: two 32-s chunks; P via packed b64 LDS writes, then MFMA ----
#pragma unroll
    for (int c = 0; c < 2; c++) {
#pragma unroll
      for (int nt = 0; nt < 2; nt++)
#pragma unroll
        for (int mm = 0; mm < 2; mm++) {
          int mt = c * 2 + mm;
          ushort4 pk;
          pk.x = f2bf(pv2[nt][mt][0]); pk.y = f2bf(pv2[nt][mt][1]);
          pk.z = f2bf(pv2[nt][mt][2]); pk.w = f2bf(pv2[nt][mt][3]);
          *(ushort4*)(Pw + (nt * 16 + fr) * 80 + mm * 32 + quad * 8) = pk;
        }
      bf16x8_t ap0 = *(const bf16x8_t*)(Pw + fr * 80 + quad * 16);
      bf16x8_t ap1 = *(const bf16x8_t*)(Pw + (16 + fr) * 80 + quad * 16);
#pragma unroll
      for (int nd = 0; nd < 4; nd++) {
        bf16x8_t bv = *(const bf16x8_t*)(Vc + (size_t)(nd * 16 + fr) * 1024
                                         + (((sb + c * 32) * 2 + quad * 16) ^ kxor));
        O[0][nd] = __builtin_amdgcn_mfma_f32_16x16x32_bf16(ap0, bv, O[0][nd], 0, 0, 0);
        O[1][nd] = __builtin_amdgcn_mfma_f32_16x16x32_bf16(ap1, bv, O[1][nd], 0, 0, 0);
      }
    }
  }

  // ---- epilogue: O / l * nm ----
#pragma unroll
  for (int mp = 0; mp < 2; mp++) {
    const int p0 = wave * 32 + mp * 16 + quad * 4;
#pragma unroll
    for (int r = 0; r < 4; r++) {
      float lb = __shfl(l_run[mp], quad * 4 + r, 64);
      float nm = nmask[b * 256 + p0 + r];
      float scl = nm / lb;
#pragma unroll
      for (int nd = 0; nd < 4; nd++)
        outA[(size_t)(b * 256 + p0 + r) * 768 + h * 64 + nd * 16 + fr] = O[mp][nd][r] * scl;
    }
  }
}

extern "C" void kernel_launch(void* const* d_in, const int* in_sizes, int n_in,
                              void* d_out, int out_size, void* d_ws, size_t ws_size,
                              hipStream_t stream) {
  const float* hs   = (const float*)d_in[0];
  const int*   mask = (const int*)d_in[1];
  const float* W    = (const float*)d_in[2];
  const float* bias = (const float*)d_in[3];
  float* out = (float*)d_out;
  char* ws = (char*)d_ws;
  // ws layout (bytes): A_bf16 [0, 50331648) ; Wt [50331648, 53870592) ;
  //                    qkv_bf16 [53870592, 204865536). qp aliases A (A dead after GEMM).
  ushort* A   = (ushort*)(ws);
  ushort* Wt  = (ushort*)(ws + 50331648);
  ushort* qkv = (ushort*)(ws + 53870592);
  ushort* qp  = (ushort*)(ws);

  hipLaunchKernelGGL(cast_hs_kernel, dim3(24576), dim3(256), 0, stream, hs, A);
  hipLaunchKernelGGL(transpose_w_kernel, dim3(72, 24), dim3(256), 0, stream, W, Wt);
  hipLaunchKernelGGL(gemm_qkv_kernel, dim3(1152), dim3(512), 0, stream, A, Wt, bias, mask, qkv);
  hipLaunchKernelGGL(pool_kernel, dim3(12288), dim3(256), 0, stream, qkv, mask, out, qp);
  hipLaunchKernelGGL(attn_kernel, dim3(12, 64), dim3(512), 0, stream,
                     qkv, qp, mask, out + 12582912, out);
}

// Round 5
// 414.501 us; speedup vs baseline: 1.2921x; 1.0041x over previous
//
#include <hip/hip_runtime.h>
#include <cstdint>
#include <cstddef>

#define HH 12
#define DHD 64
#define BB 64
#define SS 512
#define DD 768
#define PP 256
#define N3 2304

typedef __attribute__((ext_vector_type(8))) short bf16x8_t;
typedef __attribute__((ext_vector_type(4))) float f32x4_t;

__constant__ float c_slopes[12] = {
  0.5f, 0.25f, 0.125f, 0.0625f, 0.03125f, 0.015625f, 0.0078125f, 0.00390625f,
  0.70710678118654752f, 0.35355339059327376f, 0.17677669529663688f, 0.08838834764831844f
};

__device__ __forceinline__ ushort f2bf(float f) {
  union { float f; unsigned u; } v; v.f = f;
  unsigned r = v.u + 0x7fffu + ((v.u >> 16) & 1u);  // RNE
  return (ushort)(r >> 16);
}
__device__ __forceinline__ float bf2f(ushort u) {
  union { unsigned u; float f; } v; v.u = ((unsigned)u) << 16;
  return v.f;
}
__device__ __forceinline__ void gload_lds16(const ushort* g, ushort* l) {
  __builtin_amdgcn_global_load_lds(
      (const __attribute__((address_space(1))) void*)g,
      (__attribute__((address_space(3))) void*)l, 16, 0, 0);
}

// ---------------- prep: cast hidden_states fp32->bf16  +  transpose/cast W ----------------
// blocks [0, 24576): cast 64*512*768 floats (float4 granular).
// blocks [24576, 26304): 32x32 transpose tiles of W (768x2304) -> Wt bf16 (2304x768).
__global__ __launch_bounds__(256) void prep_kernel(const float* __restrict__ in,
                                                   ushort* __restrict__ out,
                                                   const float* __restrict__ W,
                                                   ushort* __restrict__ Wt) {
  if (blockIdx.x < 24576) {
    int i = blockIdx.x * 256 + threadIdx.x;        // exactly 6291456 float4 groups
    float4 v = ((const float4*)in)[i];
    ushort4 o;
    o.x = f2bf(v.x); o.y = f2bf(v.y); o.z = f2bf(v.z); o.w = f2bf(v.w);
    ((ushort4*)out)[i] = o;
  } else {
    __shared__ float tile[32][33];
    int tb = blockIdx.x - 24576;                   // 72 * 24 tiles
    int n0 = (tb % 72) * 32, k0 = (tb / 72) * 32;
    int tx = threadIdx.x & 31, ty = threadIdx.x >> 5;
    for (int r = ty; r < 32; r += 8) tile[r][tx] = W[(size_t)(k0 + r) * N3 + n0 + tx];
    __syncthreads();
    for (int r = ty; r < 32; r += 8) Wt[(size_t)(n0 + r) * DD + k0 + tx] = f2bf(tile[tx][r]);
  }
}

// ---------------- GEMM: 256x256 tile, BK=64, 2-barrier/tile, counted-vmcnt prefetch -------
// qkv = (A.W + bias) * mask, bf16 out.  A: 32768x768 bf16, Wt: 2304x768 bf16 (N-major).
//
// LDS: As/Bs 2 buffers x 256x64 bf16 = 128KB. Linear staging via global_load_lds;
// swizzle via inverse-permuted GLOBAL source column-group (colgrp = (tid&7) ^ (row&7));
// fragment reads XOR ((fr&7)<<4) bytes -> 0 bank conflicts (verified rocprof r3).
//
// Schedule per K-tile t (2-deep prefetch, buffers alternate t&1):
//   [one compiler-scheduled region: 24 ds_read_b128 + 64 MFMA, fine lgkmcnt interleave]
//   lgkmcnt(0) + sched_barrier(0)      // seal: no read sinks past the barrier
//   s_barrier                          // all waves done READING buf[t&1]
//   stage tile t+2 -> buf[t&1]         // WAR-safe now
//   vmcnt(8)                           // tile t+1's 8 loads retired; t+2 stays in flight
//   s_barrier
// Raw s_barrier (not __syncthreads) keeps the global_load_lds queue un-drained.
__global__ __launch_bounds__(512, 2) void gemm_qkv_kernel(
    const ushort* __restrict__ A, const ushort* __restrict__ Wt,
    const float* __restrict__ bias, const int* __restrict__ mask,
    ushort* __restrict__ qkv) {
  __shared__ __align__(16) ushort As[2][16384];
  __shared__ __align__(16) ushort Bs[2][16384];
  // XCD-aware swizzle: 1152 blocks, 1152%8==0 -> bijective.
  const int wg = blockIdx.x;
  const int swz = (wg & 7) * 144 + (wg >> 3);
  const int bm = (swz / 9) * 256;
  const int bn = (swz % 9) * 256;
  const int tid = threadIdx.x;
  const int lane = tid & 63;
  const int wave = tid >> 6;
  const int wm = (wave >> 2) * 128;       // 2 M-halves
  const int wn = (wave & 3) * 64;         // 4 N-quarters
  const int fr = lane & 15, quad = lane >> 4;
  const int xr = (fr & 7) << 3;           // swizzle XOR in ushort units
  const int q8 = quad * 8;

  const int rsub = tid >> 3;
  const int cg8 = ((tid & 7) ^ (rsub & 7)) * 8;
  const ushort* Ag = A  + (size_t)(bm + rsub) * DD + cg8;
  const ushort* Bg = Wt + (size_t)(bn + rsub) * DD + cg8;
  ushort* AsW = &As[0][0] + wave * 512;
  ushort* BsW = &Bs[0][0] + wave * 512;

  f32x4_t acc[8][4];
#pragma unroll
  for (int i = 0; i < 8; i++)
#pragma unroll
    for (int j = 0; j < 4; j++) acc[i][j] = (f32x4_t){0.f, 0.f, 0.f, 0.f};

  // prologue: stage tile 0 -> buf0, tile 1 -> buf1 (16 loads), wait for tile 0 only
#pragma unroll
  for (int l = 0; l < 4; l++) {
    gload_lds16(Ag + (size_t)l * 64 * DD,      AsW + l * 4096);
    gload_lds16(Bg + (size_t)l * 64 * DD,      BsW + l * 4096);
  }
#pragma unroll
  for (int l = 0; l < 4; l++) {
    gload_lds16(Ag + (size_t)l * 64 * DD + 64, AsW + 16384 + l * 4096);
    gload_lds16(Bg + (size_t)l * 64 * DD + 64, BsW + 16384 + l * 4096);
  }
  asm volatile("s_waitcnt vmcnt(8)" ::: "memory");
  __builtin_amdgcn_s_barrier();
  asm volatile("" ::: "memory");

#pragma unroll 2
  for (int t = 0; t < 12; t++) {
    const ushort* Ab = &As[t & 1][0];
    const ushort* Bb = &Bs[t & 1][0];
    bf16x8_t a[4][2], b[4][2];
    // ---- one region: reads + MFMA, compiler-interleaved ----
#pragma unroll
    for (int m = 0; m < 4; m++)
#pragma unroll
      for (int kk = 0; kk < 2; kk++)
        a[m][kk] = *(const bf16x8_t*)&Ab[(wm + m * 16 + fr) * 64 + ((kk * 32 + q8) ^ xr)];
#pragma unroll
    for (int n = 0; n < 4; n++)
#pragma unroll
      for (int kk = 0; kk < 2; kk++)
        b[n][kk] = *(const bf16x8_t*)&Bb[(wn + n * 16 + fr) * 64 + ((kk * 32 + q8) ^ xr)];
#pragma unroll
    for (int m = 0; m < 4; m++)
#pragma unroll
      for (int n = 0; n < 4; n++) {
        acc[m][n] = __builtin_amdgcn_mfma_f32_16x16x32_bf16(a[m][0], b[n][0], acc[m][n], 0, 0, 0);
        acc[m][n] = __builtin_amdgcn_mfma_f32_16x16x32_bf16(a[m][1], b[n][1], acc[m][n], 0, 0, 0);
      }
#pragma unroll
    for (int m = 0; m < 4; m++)
#pragma unroll
      for (int kk = 0; kk < 2; kk++)
        a[m][kk] = *(const bf16x8_t*)&Ab[(wm + 64 + m * 16 + fr) * 64 + ((kk * 32 + q8) ^ xr)];
#pragma unroll
    for (int m = 0; m < 4; m++)
#pragma unroll
      for (int n = 0; n < 4; n++) {
        acc[4 + m][n] = __builtin_amdgcn_mfma_f32_16x16x32_bf16(a[m][0], b[n][0], acc[4 + m][n], 0, 0, 0);
        acc[4 + m][n] = __builtin_amdgcn_mfma_f32_16x16x32_bf16(a[m][1], b[n][1], acc[4 + m][n], 0, 0, 0);
      }
    // ---- seal region: all reads of buf[t&1] complete, nothing sinks past ----
    asm volatile("s_waitcnt lgkmcnt(0)" ::: "memory");
    __builtin_amdgcn_sched_barrier(0);
    __builtin_amdgcn_s_barrier();
    // ---- stage tile t+2 into buf[t&1]; counted vmcnt retires tile t+1 ----
    if (t < 10) {
      const size_t koff = (size_t)(t + 2) * 64;
      ushort* Ad = AsW + (t & 1) * 16384;
      ushort* Bd = BsW + (t & 1) * 16384;
#pragma unroll
      for (int l = 0; l < 4; l++) {
        gload_lds16(Ag + (size_t)l * 64 * DD + koff, Ad + l * 4096);
        gload_lds16(Bg + (size_t)l * 64 * DD + koff, Bd + l * 4096);
      }
      asm volatile("s_waitcnt vmcnt(8)" ::: "memory");
    } else {
      asm volatile("s_waitcnt vmcnt(0)" ::: "memory");
    }
    __builtin_amdgcn_s_barrier();
    asm volatile("" ::: "memory");
  }

  // ---- epilogue: (acc + bias) * mask -> bf16 ----
  float bb[4];
#pragma unroll
  for (int j = 0; j < 4; j++) bb[j] = bias[bn + wn + j * 16 + fr];
#pragma unroll
  for (int i = 0; i < 8; i++) {
    const int gm = bm + wm + i * 16 + quad * 4;
#pragma unroll
    for (int r = 0; r < 4; r++) {
      const float mv = (float)mask[gm + r];
      ushort* orow = qkv + (size_t)(gm + r) * N3 + bn + wn + fr;
#pragma unroll
      for (int j = 0; j < 4; j++)
        orow[j * 16] = f2bf((acc[i][j][r] + bb[j]) * mv);
    }
  }
}

// ---------------- pool: q_pooled, residual, new_mask ----------------
__global__ void pool_kernel(const ushort* __restrict__ qkv, const int* __restrict__ mask,
                            float* __restrict__ out, ushort* __restrict__ qp) {
  int idx = blockIdx.x * 256 + threadIdx.x;       // 64*256*192 total
  int d4 = idx % 192;
  int bp = idx / 192;
  int b = bp >> 8, p = bp & 255;
  int m0 = mask[b*512 + 2*p], m1 = mask[b*512 + 2*p + 1];
  int ms = m0 + m1;
  float inv = 1.0f / (float)(ms < 1 ? 1 : ms);
  const ushort* r0 = qkv + (size_t)(b*512 + 2*p) * N3 + d4*4;
  ushort4 x0 = *(const ushort4*)r0;
  ushort4 x1 = *(const ushort4*)(r0 + N3);
  float y0 = (bf2f(x0.x) + bf2f(x1.x)) * inv;
  float y1 = (bf2f(x0.y) + bf2f(x1.y)) * inv;
  float y2 = (bf2f(x0.z) + bf2f(x1.z)) * inv;
  float y3 = (bf2f(x0.w) + bf2f(x1.w)) * inv;
  float4 y = {y0, y1, y2, y3};
  *(float4*)(out + 12599296 + (size_t)bp * 768 + d4*4) = y;    // residual_query (==0 when masked)
  ushort4 q8;                                                   // fold 1/sqrt(DH)=1/8 into bf16 q
  q8.x = f2bf(y0 * 0.125f); q8.y = f2bf(y1 * 0.125f);
  q8.z = f2bf(y2 * 0.125f); q8.w = f2bf(y3 * 0.125f);
  *(ushort4*)(qp + (size_t)bp * 768 + d4*4) = q8;
  if (d4 == 0) out[12582912 + bp] = (ms > 0) ? 1.0f : 0.0f;     // new_mask
}

// ---------------- attention: one block per (h,b), flash-style, LDS-resident K/V^T --------
__global__ __launch_bounds__(512, 2) void attn_kernel(
    const ushort* __restrict__ qkv, const ushort* __restrict__ qp,
    const int* __restrict__ mask, const float* __restrict__ nmask,
    float* __restrict__ outA) {
  __shared__ __align__(16) ushort K_lds[512 * 64];
  __shared__ __align__(16) ushort VT_lds[64 * 512];
  __shared__ __align__(16) ushort P_lds[8][32][40];
  __shared__ __align__(16) float  kb[512];
  const int h = blockIdx.x, b = blockIdx.y;
  const int tid = threadIdx.x, wave = tid >> 6, lane = tid & 63;
  const int fr = lane & 15, quad = lane >> 4;
  const int kxor = (fr & 7) << 4;                 // byte-XOR for swizzled LDS reads
  const float slope = c_slopes[h];

  // ---- stage K (global_load_lds, 8 instrs/wave, rows wave*64..+64) ----
  {
    const int r0 = lane >> 3;
    const int cg = ((lane & 7) ^ r0) * 8;         // inverse-swizzled source chunk
    const ushort* Ks = qkv + (size_t)(b * 512 + wave * 64 + r0) * N3 + 768 + h * 64 + cg;
#pragma unroll
    for (int i = 0; i < 8; i++)
      gload_lds16(Ks + (size_t)i * 8 * N3, K_lds + (wave * 64 + i * 8) * 64);
  }
  // ---- stage V^T (reg-staged, swizzled scalar writes; once per block) ----
  {
    const ushort* Vs = qkv + (size_t)(b * 512 + tid) * N3 + 1536 + h * 64;
    float4 vr[8];
#pragma unroll
    for (int d0 = 0; d0 < 8; d0++) vr[d0] = *(const float4*)(Vs + d0 * 8);
    const int s2 = tid * 2;                       // byte col in VT row
    const int sbase = (s2 & ~15), slo = (s2 & 15);
#pragma unroll
    for (int d0 = 0; d0 < 8; d0++) {
      ushort tmp[8];
      *(float4*)tmp = vr[d0];
#pragma unroll
      for (int j = 0; j < 8; j++) {
        int d = d0 * 8 + j;
        *(ushort*)((char*)VT_lds + (size_t)d * 1024 + ((sbase ^ ((d & 7) << 4)) + slo)) = tmp[j];
      }
    }
  }
  kb[tid] = mask[b * 512 + tid] ? 0.0f : -10000.0f;
  // ---- Q fragments (B-operand rows p, direct from global) ----
  bf16x8_t qf[2][2];
#pragma unroll
  for (int nt = 0; nt < 2; nt++)
#pragma unroll
    for (int ks = 0; ks < 2; ks++)
      qf[nt][ks] = *(const bf16x8_t*)(qp + (size_t)(b * 256 + wave * 32 + nt * 16 + fr) * 768
                                      + h * 64 + ks * 32 + quad * 8);
  __syncthreads();   // drains vmcnt+lgkmcnt: K gload_lds + VT/kb writes all visible

  const char* Kc = (const char*)K_lds;
  const char* Vc = (const char*)VT_lds;
  char* Pw = (char*)&P_lds[wave][0][0];

  f32x4_t O[2][4];
#pragma unroll
  for (int i = 0; i < 2; i++)
#pragma unroll
    for (int j = 0; j < 4; j++) O[i][j] = (f32x4_t){0.f, 0.f, 0.f, 0.f};
  float m_run[2] = {-3.0e38f, -3.0e38f};
  float l_run[2] = {0.f, 0.f};

  for (int sb = 0; sb < 512; sb += 64) {
    // ---- QK^T (swapped): S^T[s][p], 8 LDS reads + 16 MFMA ----
    f32x4_t sacc[4][2];
#pragma unroll
    for (int mt = 0; mt < 4; mt++) { sacc[mt][0] = (f32x4_t){0,0,0,0}; sacc[mt][1] = (f32x4_t){0,0,0,0}; }
#pragma unroll
    for (int ks = 0; ks < 2; ks++)
#pragma unroll
      for (int mt = 0; mt < 4; mt++) {
        bf16x8_t ak = *(const bf16x8_t*)(Kc + (size_t)(sb + mt * 16 + fr) * 128
                                         + ((ks * 64 + quad * 16) ^ kxor));
        sacc[mt][0] = __builtin_amdgcn_mfma_f32_16x16x32_bf16(ak, qf[0][ks], sacc[mt][0], 0, 0, 0);
        sacc[mt][1] = __builtin_amdgcn_mfma_f32_16x16x32_bf16(ak, qf[1][ks], sacc[mt][1], 0, 0, 0);
      }
    // ---- bias + online softmax (per nt = p-half) ----
    float kbv[4][4];
#pragma unroll
    for (int mt = 0; mt < 4; mt++) {
      f32x4_t kv = *(const f32x4_t*)&kb[sb + mt * 16 + quad * 4];
#pragma unroll
      for (int r = 0; r < 4; r++) kbv[mt][r] = kv[r];
    }
    float pv2[2][4][4];
    float fsv[2];
#pragma unroll
    for (int nt = 0; nt < 2; nt++) {
      const float pidx = (float)(wave * 32 + nt * 16 + fr);
      float mx = -3.0e38f;
#pragma unroll
      for (int mt = 0; mt < 4; mt++)
#pragma unroll
        for (int r = 0; r < 4; r++) {
          float s_ = (float)(sb + mt * 16 + quad * 4 + r);
          float v = sacc[mt][nt][r] + kbv[mt][r] - slope * fabsf(s_ - pidx);
          pv2[nt][mt][r] = v;
          mx = fmaxf(mx, v);
        }
      mx = fmaxf(mx, __shfl_xor(mx, 16, 64));
      mx = fmaxf(mx, __shfl_xor(mx, 32, 64));
      float mnew = fmaxf(m_run[nt], mx);
      float f = __expf(m_run[nt] - mnew);
      m_run[nt] = mnew; fsv[nt] = f;
      float rs = 0.f;
#pragma unroll
      for (int mt = 0; mt < 4; mt++)
#pragma unroll
        for (int r = 0; r < 4; r++) {
          float e = __expf(pv2[nt][mt][r] - mnew);
          pv2[nt][mt][r] = e; rs += e;
        }
      rs += __shfl_xor(rs, 16, 64);
      rs += __shfl_xor(rs, 32, 64);
      l_run[nt] = l_run[nt] * f + rs;
    }
    // ---- rescale O (factor redistributed via shfl: row p needs lane quad*4+r) ----
#pragma unroll
    for (int mp = 0; mp < 2; mp++)
#pragma unroll
      for (int r = 0; r < 4; r++) {
        float fb = __shfl(fsv[mp], quad * 4 + r, 64);
#pragma unroll
        for (int nd = 0; nd < 4; nd++) O[mp][nd][r] *= fb;
      }
    // ---- PV: two 32-s chunks; P via packed b64 LDS writes, then MFMA ----
#pragma unroll
    for (int c = 0; c < 2; c++) {
#pragma unroll
      for (int nt = 0; nt < 2; nt++)
#pragma unroll
        for (int mm = 0; mm < 2; mm++) {
          int mt = c * 2 + mm;
          ushort4 pk;
          pk.x = f2bf(pv2[nt][mt][0]); pk.y = f2bf(pv2[nt][mt][1]);
          pk.z = f2bf(pv2[nt][mt][2]); pk.w = f2bf(pv2[nt][mt][3]);
          *(ushort4*)(Pw + (nt * 16 + fr) * 80 + mm * 32 + quad * 8) = pk;
        }
      bf16x8_t ap0 = *(const bf16x8_t*)(Pw + fr * 80 + quad * 16);
      bf16x8_t ap1 = *(const bf16x8_t*)(Pw + (16 + fr) * 80 + quad * 16);
#pragma unroll
      for (int nd = 0; nd < 4; nd++) {
        bf16x8_t bv = *(const bf16x8_t*)(Vc + (size_t)(nd * 16 + fr) * 1024
                                         + (((sb + c * 32) * 2 + quad * 16) ^ kxor));
        O[0][nd] = __builtin_amdgcn_mfma_f32_16x16x32_bf16(ap0, bv, O[0][nd], 0, 0, 0);
        O[1][nd] = __builtin_amdgcn_mfma_f32_16x16x32_bf16(ap1, bv, O[1][nd], 0, 0, 0);
      }
    }
  }

  // ---- epilogue: O / l * nm ----
#pragma unroll
  for (int mp = 0; mp < 2; mp++) {
    const int p0 = wave * 32 + mp * 16 + quad * 4;
#pragma unroll
    for (int r = 0; r < 4; r++) {
      float lb = __shfl(l_run[mp], quad * 4 + r, 64);
      float nm = nmask[b * 256 + p0 + r];
      float scl = nm / lb;
#pragma unroll
      for (int nd = 0; nd < 4; nd++)
        outA[(size_t)(b * 256 + p0 + r) * 768 + h * 64 + nd * 16 + fr] = O[mp][nd][r] * scl;
    }
  }
}

extern "C" void kernel_launch(void* const* d_in, const int* in_sizes, int n_in,
                              void* d_out, int out_size, void* d_ws, size_t ws_size,
                              hipStream_t stream) {
  const float* hs   = (const float*)d_in[0];
  const int*   mask = (const int*)d_in[1];
  const float* W    = (const float*)d_in[2];
  const float* bias = (const float*)d_in[3];
  float* out = (float*)d_out;
  char* ws = (char*)d_ws;
  // ws layout (bytes): A_bf16 [0, 50331648) ; Wt [50331648, 53870592) ;
  //                    qkv_bf16 [53870592, 204865536). qp aliases A (A dead after GEMM).
  ushort* A   = (ushort*)(ws);
  ushort* Wt  = (ushort*)(ws + 50331648);
  ushort* qkv = (ushort*)(ws + 53870592);
  ushort* qp  = (ushort*)(ws);

  hipLaunchKernelGGL(prep_kernel, dim3(26304), dim3(256), 0, stream, hs, A, W, Wt);
  hipLaunchKernelGGL(gemm_qkv_kernel, dim3(1152), dim3(512), 0, stream, A, Wt, bias, mask, qkv);
  hipLaunchKernelGGL(pool_kernel, dim3(12288), dim3(256), 0, stream, qkv, mask, out, qp);
  hipLaunchKernelGGL(attn_kernel, dim3(12, 64), dim3(512), 0, stream,
                     qkv, qp, mask, out + 12582912, out);
}

// Round 7
// 389.836 us; speedup vs baseline: 1.3739x; 1.0633x over previous
//
#include <hip/hip_runtime.h>
#include <cstdint>
#include <cstddef>

#define HH 12
#define DHD 64
#define BB 64
#define SS 512
#define DD 768
#define PP 256
#define N3 2304

typedef __attribute__((ext_vector_type(8))) short bf16x8_t;
typedef __attribute__((ext_vector_type(4))) float f32x4_t;

__constant__ float c_slopes[12] = {
  0.5f, 0.25f, 0.125f, 0.0625f, 0.03125f, 0.015625f, 0.0078125f, 0.00390625f,
  0.70710678118654752f, 0.35355339059327376f, 0.17677669529663688f, 0.08838834764831844f
};

__device__ __forceinline__ ushort f2bf(float f) {
  union { float f; unsigned u; } v; v.f = f;
  unsigned r = v.u + 0x7fffu + ((v.u >> 16) & 1u);  // RNE
  return (ushort)(r >> 16);
}
__device__ __forceinline__ float bf2f(ushort u) {
  union { unsigned u; float f; } v; v.u = ((unsigned)u) << 16;
  return v.f;
}
__device__ __forceinline__ void gload_lds16(const ushort* g, ushort* l) {
  __builtin_amdgcn_global_load_lds(
      (const __attribute__((address_space(1))) void*)g,
      (__attribute__((address_space(3))) void*)l, 16, 0, 0);
}

// ---------------- prep: cast hs -> A bf16, masked-pool hs -> Ap bf16, new_mask,
//                  and transpose/cast W -> Wt.
// Pool algebra: q_pooled = pool_m(h).Wq + bq*1[ms>0]  (masked-linear commutes with GEMM),
// so Ap[b*256+p] = (m0*h[2p] + m1*h[2p+1]) / max(m0+m1,1), pooled in fp32.
// blocks [0, 8192): 4 hs rows each (2 pool pairs). blocks [8192, 9920): W transpose tiles.
__global__ __launch_bounds__(256) void prep_kernel(
    const float* __restrict__ hs, const int* __restrict__ mask,
    ushort* __restrict__ A, ushort* __restrict__ Ap,
    const float* __restrict__ W, ushort* __restrict__ Wt,
    float* __restrict__ nmask_out) {
  if (blockIdx.x < 8192) {
    const int row0 = blockIdx.x * 4;               // global hs row, pair-aligned
    const int t = threadIdx.x;
    if (t < 192) {                                 // 192 float4 per row
      float4 v[4];
#pragma unroll
      for (int r = 0; r < 4; r++) {
        v[r] = ((const float4*)hs)[(size_t)(row0 + r) * 192 + t];
        ushort4 o;
        o.x = f2bf(v[r].x); o.y = f2bf(v[r].y); o.z = f2bf(v[r].z); o.w = f2bf(v[r].w);
        ((ushort4*)A)[(size_t)(row0 + r) * 192 + t] = o;
      }
      const int m0 = mask[row0], m1 = mask[row0 + 1];
      const int m2 = mask[row0 + 2], m3 = mask[row0 + 3];
      const float f0 = (float)m0, f1 = (float)m1, f2 = (float)m2, f3 = (float)m3;
      const float inv0 = 1.0f / (float)((m0 + m1) < 1 ? 1 : (m0 + m1));
      const float inv1 = 1.0f / (float)((m2 + m3) < 1 ? 1 : (m2 + m3));
      ushort4 p0, p1;
      p0.x = f2bf((f0 * v[0].x + f1 * v[1].x) * inv0);
      p0.y = f2bf((f0 * v[0].y + f1 * v[1].y) * inv0);
      p0.z = f2bf((f0 * v[0].z + f1 * v[1].z) * inv0);
      p0.w = f2bf((f0 * v[0].w + f1 * v[1].w) * inv0);
      p1.x = f2bf((f2 * v[2].x + f3 * v[3].x) * inv1);
      p1.y = f2bf((f2 * v[2].y + f3 * v[3].y) * inv1);
      p1.z = f2bf((f2 * v[2].z + f3 * v[3].z) * inv1);
      p1.w = f2bf((f2 * v[2].w + f3 * v[3].w) * inv1);
      const int prow = row0 >> 1;
      ((ushort4*)Ap)[(size_t)prow * 192 + t]       = p0;
      ((ushort4*)Ap)[(size_t)(prow + 1) * 192 + t] = p1;
      if (t == 0) {
        nmask_out[prow]     = (m0 + m1) > 0 ? 1.0f : 0.0f;
        nmask_out[prow + 1] = (m2 + m3) > 0 ? 1.0f : 0.0f;
      }
    }
  } else {
    __shared__ float tile[32][33];
    int tb = blockIdx.x - 8192;                    // 72 * 24 tiles
    int n0 = (tb % 72) * 32, k0 = (tb / 72) * 32;
    int tx = threadIdx.x & 31, ty = threadIdx.x >> 5;
    for (int r = ty; r < 32; r += 8) tile[r][tx] = W[(size_t)(k0 + r) * N3 + n0 + tx];
    __syncthreads();
    for (int r = ty; r < 32; r += 8) Wt[(size_t)(n0 + r) * DD + k0 + tx] = f2bf(tile[tx][r]);
  }
}

// ---------------- GEMM: 256x256 tile, BK=64, 2-barrier/tile, counted-vmcnt prefetch -------
// Unified KV+Q dispatch (960 blocks = 8x120, XCD-bijective):
//   swz <  768: KV part. A rows (M=32768), Wt rows 768+; -> Kbuf/Vbuf bf16 [32768][768],
//               epilogue * mask[row].
//   swz >= 768: Q part.  Ap rows (M=16384), Wt rows 0..767; v = acc + bias*nmask[row];
//               -> resid fp32 (== residual_query) and qp = f2bf(v/8).
// LDS/swizzle/schedule identical to r5 (0 bank conflicts verified).
__global__ __launch_bounds__(512, 2) void gemm_qkv_kernel(
    const ushort* __restrict__ A, const ushort* __restrict__ Ap,
    const ushort* __restrict__ Wt, const float* __restrict__ bias,
    const int* __restrict__ mask, const float* __restrict__ nmask,
    ushort* __restrict__ Kbuf, ushort* __restrict__ Vbuf,
    float* __restrict__ resid, ushort* __restrict__ qp) {
  __shared__ __align__(16) ushort As[2][16384];
  __shared__ __align__(16) ushort Bs[2][16384];
  const int wg = blockIdx.x;
  const int swz = (wg & 7) * 120 + (wg >> 3);
  int bm, wtb; const ushort* Asrc; bool isQ;
  if (swz < 768) { isQ = false; bm = (swz / 6) * 256; wtb = 768 + (swz % 6) * 256; Asrc = A; }
  else { isQ = true; int q = swz - 768; bm = (q / 3) * 256; wtb = (q % 3) * 256; Asrc = Ap; }
  const int tid = threadIdx.x;
  const int lane = tid & 63;
  const int wave = tid >> 6;
  const int wm = (wave >> 2) * 128;       // 2 M-halves
  const int wn = (wave & 3) * 64;         // 4 N-quarters
  const int fr = lane & 15, quad = lane >> 4;
  const int xr = (fr & 7) << 3;           // swizzle XOR in ushort units
  const int q8 = quad * 8;

  const int rsub = tid >> 3;
  const int cg8 = ((tid & 7) ^ (rsub & 7)) * 8;
  const ushort* Ag = Asrc + (size_t)(bm + rsub) * DD + cg8;
  const ushort* Bg = Wt + (size_t)(wtb + rsub) * DD + cg8;
  ushort* AsW = &As[0][0] + wave * 512;
  ushort* BsW = &Bs[0][0] + wave * 512;

  f32x4_t acc[8][4];
#pragma unroll
  for (int i = 0; i < 8; i++)
#pragma unroll
    for (int j = 0; j < 4; j++) acc[i][j] = (f32x4_t){0.f, 0.f, 0.f, 0.f};

  // prologue: stage tile 0 -> buf0, tile 1 -> buf1 (16 loads), wait for tile 0 only
#pragma unroll
  for (int l = 0; l < 4; l++) {
    gload_lds16(Ag + (size_t)l * 64 * DD,      AsW + l * 4096);
    gload_lds16(Bg + (size_t)l * 64 * DD,      BsW + l * 4096);
  }
#pragma unroll
  for (int l = 0; l < 4; l++) {
    gload_lds16(Ag + (size_t)l * 64 * DD + 64, AsW + 16384 + l * 4096);
    gload_lds16(Bg + (size_t)l * 64 * DD + 64, BsW + 16384 + l * 4096);
  }
  asm volatile("s_waitcnt vmcnt(8)" ::: "memory");
  __builtin_amdgcn_s_barrier();
  asm volatile("" ::: "memory");

#pragma unroll 2
  for (int t = 0; t < 12; t++) {
    const ushort* Ab = &As[t & 1][0];
    const ushort* Bb = &Bs[t & 1][0];
    bf16x8_t a[4][2], b[4][2];
#pragma unroll
    for (int m = 0; m < 4; m++)
#pragma unroll
      for (int kk = 0; kk < 2; kk++)
        a[m][kk] = *(const bf16x8_t*)&Ab[(wm + m * 16 + fr) * 64 + ((kk * 32 + q8) ^ xr)];
#pragma unroll
    for (int n = 0; n < 4; n++)
#pragma unroll
      for (int kk = 0; kk < 2; kk++)
        b[n][kk] = *(const bf16x8_t*)&Bb[(wn + n * 16 + fr) * 64 + ((kk * 32 + q8) ^ xr)];
#pragma unroll
    for (int m = 0; m < 4; m++)
#pragma unroll
      for (int n = 0; n < 4; n++) {
        acc[m][n] = __builtin_amdgcn_mfma_f32_16x16x32_bf16(a[m][0], b[n][0], acc[m][n], 0, 0, 0);
        acc[m][n] = __builtin_amdgcn_mfma_f32_16x16x32_bf16(a[m][1], b[n][1], acc[m][n], 0, 0, 0);
      }
#pragma unroll
    for (int m = 0; m < 4; m++)
#pragma unroll
      for (int kk = 0; kk < 2; kk++)
        a[m][kk] = *(const bf16x8_t*)&Ab[(wm + 64 + m * 16 + fr) * 64 + ((kk * 32 + q8) ^ xr)];
#pragma unroll
    for (int m = 0; m < 4; m++)
#pragma unroll
      for (int n = 0; n < 4; n++) {
        acc[4 + m][n] = __builtin_amdgcn_mfma_f32_16x16x32_bf16(a[m][0], b[n][0], acc[4 + m][n], 0, 0, 0);
        acc[4 + m][n] = __builtin_amdgcn_mfma_f32_16x16x32_bf16(a[m][1], b[n][1], acc[4 + m][n], 0, 0, 0);
      }
    asm volatile("s_waitcnt lgkmcnt(0)" ::: "memory");
    __builtin_amdgcn_sched_barrier(0);
    __builtin_amdgcn_s_barrier();
    if (t < 10) {
      const size_t koff = (size_t)(t + 2) * 64;
      ushort* Ad = AsW + (t & 1) * 16384;
      ushort* Bd = BsW + (t & 1) * 16384;
#pragma unroll
      for (int l = 0; l < 4; l++) {
        gload_lds16(Ag + (size_t)l * 64 * DD + koff, Ad + l * 4096);
        gload_lds16(Bg + (size_t)l * 64 * DD + koff, Bd + l * 4096);
      }
      asm volatile("s_waitcnt vmcnt(8)" ::: "memory");
    } else {
      asm volatile("s_waitcnt vmcnt(0)" ::: "memory");
    }
    __builtin_amdgcn_s_barrier();
    asm volatile("" ::: "memory");
  }

  // ---- epilogue ----
  float bb[4];
#pragma unroll
  for (int j = 0; j < 4; j++) bb[j] = bias[wtb + wn + j * 16 + fr];
  if (!isQ) {
    ushort* dst = (wtb < 1536) ? Kbuf : Vbuf;
    const int cb = (wtb < 1536) ? (wtb - 768) : (wtb - 1536);
#pragma unroll
    for (int i = 0; i < 8; i++) {
      const int gm = bm + wm + i * 16 + quad * 4;
#pragma unroll
      for (int r = 0; r < 4; r++) {
        const float mv = (float)mask[gm + r];
        ushort* orow = dst + (size_t)(gm + r) * DD + cb + wn + fr;
#pragma unroll
        for (int j = 0; j < 4; j++)
          orow[j * 16] = f2bf((acc[i][j][r] + bb[j]) * mv);
      }
    }
  } else {
#pragma unroll
    for (int i = 0; i < 8; i++) {
      const int gm = bm + wm + i * 16 + quad * 4;
#pragma unroll
      for (int r = 0; r < 4; r++) {
        const float qm = nmask[gm + r];
        float* rrow = resid + (size_t)(gm + r) * DD + wtb + wn + fr;
        ushort* qrow = qp + (size_t)(gm + r) * DD + wtb + wn + fr;
#pragma unroll
        for (int j = 0; j < 4; j++) {
          float v = acc[i][j][r] + bb[j] * qm;
          rrow[j * 16] = v;
          qrow[j * 16] = f2bf(v * 0.125f);
        }
      }
    }
  }
}

// ---------------- attention: one block per (h,b), flash-style, LDS-resident K/V^T --------
// K/V read from compact [32768][768] bf16 buffers (stride 768).
__global__ __launch_bounds__(512, 2) void attn_kernel(
    const ushort* __restrict__ Kbuf, const ushort* __restrict__ Vbuf,
    const ushort* __restrict__ qp,
    const int* __restrict__ mask, const float* __restrict__ nmask,
    float* __restrict__ outA) {
  __shared__ __align__(16) ushort K_lds[512 * 64];
  __shared__ __align__(16) ushort VT_lds[64 * 512];
  __shared__ __align__(16) ushort P_lds[8][32][40];
  __shared__ __align__(16) float  kb[512];
  const int h = blockIdx.x, b = blockIdx.y;
  const int tid = threadIdx.x, wave = tid >> 6, lane = tid & 63;
  const int fr = lane & 15, quad = lane >> 4;
  const int kxor = (fr & 7) << 4;                 // byte-XOR for swizzled LDS reads
  const float slope = c_slopes[h];

  // ---- stage K (global_load_lds, 8 instrs/wave, rows wave*64..+64) ----
  {
    const int r0 = lane >> 3;
    const int cg = ((lane & 7) ^ r0) * 8;         // inverse-swizzled source chunk
    const ushort* Ks = Kbuf + (size_t)(b * 512 + wave * 64 + r0) * DD + h * 64 + cg;
#pragma unroll
    for (int i = 0; i < 8; i++)
      gload_lds16(Ks + (size_t)i * 8 * DD, K_lds + (wave * 64 + i * 8) * 64);
  }
  // ---- stage V^T (reg-staged, swizzled scalar writes; once per block) ----
  {
    const ushort* Vs = Vbuf + (size_t)(b * 512 + tid) * DD + h * 64;
    float4 vr[8];
#pragma unroll
    for (int d0 = 0; d0 < 8; d0++) vr[d0] = *(const float4*)(Vs + d0 * 8);
    const int s2 = tid * 2;                       // byte col in VT row
    const int sbase = (s2 & ~15), slo = (s2 & 15);
#pragma unroll
    for (int d0 = 0; d0 < 8; d0++) {
      ushort tmp[8];
      *(float4*)tmp = vr[d0];
#pragma unroll
      for (int j = 0; j < 8; j++) {
        int d = d0 * 8 + j;
        *(ushort*)((char*)VT_lds + (size_t)d * 1024 + ((sbase ^ ((d & 7) << 4)) + slo)) = tmp[j];
      }
    }
  }
  kb[tid] = mask[b * 512 + tid] ? 0.0f : -10000.0f;
  // ---- Q fragments (B-operand rows p, direct from global) ----
  bf16x8_t qf[2][2];
#pragma unroll
  for (int nt = 0; nt < 2; nt++)
#pragma unroll
    for (int ks = 0; ks < 2; ks++)
      qf[nt][ks] = *(const bf16x8_t*)(qp + (size_t)(b * 256 + wave * 32 + nt * 16 + fr) * 768
                                      + h * 64 + ks * 32 + quad * 8);
  __syncthreads();   // drains vmcnt+lgkmcnt: K gload_lds + VT/kb writes all visible

  const char* Kc = (const char*)K_lds;
  const char* Vc = (const char*)VT_lds;
  char* Pw = (char*)&P_lds[wave][0][0];

  f32x4_t O[2][4];
#pragma unroll
  for (int i = 0; i < 2; i++)
#pragma unroll
    for (int j = 0; j < 4; j++) O[i][j] = (f32x4_t){0.f, 0.f, 0.f, 0.f};
  float m_run[2] = {-3.0e38f, -3.0e38f};
  float l_run[2] = {0.f, 0.f};

  for (int sb = 0; sb < 512; sb += 64) {
    // ---- QK^T (swapped): S^T[s][p], 8 LDS reads + 16 MFMA ----
    f32x4_t sacc[4][2];
#pragma unroll
    for (int mt = 0; mt < 4; mt++) { sacc[mt][0] = (f32x4_t){0,0,0,0}; sacc[mt][1] = (f32x4_t){0,0,0,0}; }
#pragma unroll
    for (int ks = 0; ks < 2; ks++)
#pragma unroll
      for (int mt = 0; mt < 4; mt++) {
        bf16x8_t ak = *(const bf16x8_t*)(Kc + (size_t)(sb + mt * 16 + fr) * 128
                                         + ((ks * 64 + quad * 16) ^ kxor));
        sacc[mt][0] = __builtin_amdgcn_mfma_f32_16x16x32_bf16(ak, qf[0][ks], sacc[mt][0], 0, 0, 0);
        sacc[mt][1] = __builtin_amdgcn_mfma_f32_16x16x32_bf16(ak, qf[1][ks], sacc[mt][1], 0, 0, 0);
      }
    // ---- bias + online softmax (per nt = p-half) ----
    float kbv[4][4];
#pragma unroll
    for (int mt = 0; mt < 4; mt++) {
      f32x4_t kv = *(const f32x4_t*)&kb[sb + mt * 16 + quad * 4];
#pragma unroll
      for (int r = 0; r < 4; r++) kbv[mt][r] = kv[r];
    }
    float pv2[2][4][4];
    float fsv[2];
#pragma unroll
    for (int nt = 0; nt < 2; nt++) {
      const float pidx = (float)(wave * 32 + nt * 16 + fr);
      float mx = -3.0e38f;
#pragma unroll
      for (int mt = 0; mt < 4; mt++)
#pragma unroll
        for (int r = 0; r < 4; r++) {
          float s_ = (float)(sb + mt * 16 + quad * 4 + r);
          float v = sacc[mt][nt][r] + kbv[mt][r] - slope * fabsf(s_ - pidx);
          pv2[nt][mt][r] = v;
          mx = fmaxf(mx, v);
        }
      mx = fmaxf(mx, __shfl_xor(mx, 16, 64));
      mx = fmaxf(mx, __shfl_xor(mx, 32, 64));
      float mnew = fmaxf(m_run[nt], mx);
      float f = __expf(m_run[nt] - mnew);
      m_run[nt] = mnew; fsv[nt] = f;
      float rs = 0.f;
#pragma unroll
      for (int mt = 0; mt < 4; mt++)
#pragma unroll
        for (int r = 0; r < 4; r++) {
          float e = __expf(pv2[nt][mt][r] - mnew);
          pv2[nt][mt][r] = e; rs += e;
        }
      rs += __shfl_xor(rs, 16, 64);
      rs += __shfl_xor(rs, 32, 64);
      l_run[nt] = l_run[nt] * f + rs;
    }
    // ---- rescale O (factor redistributed via shfl: row p needs lane quad*4+r) ----
#pragma unroll
    for (int mp = 0; mp < 2; mp++)
#pragma unroll
      for (int r = 0; r < 4; r++) {
        float fb = __shfl(fsv[mp], quad * 4 + r, 64);
#pragma unroll
        for (int nd = 0; nd < 4; nd++) O[mp][nd][r] *= fb;
      }
    // ---- PV: two 32-s chunks; P via packed b64 LDS writes, then MFMA ----
#pragma unroll
    for (int c = 0; c < 2; c++) {
#pragma unroll
      for (int nt = 0; nt < 2; nt++)
#pragma unroll
        for (int mm = 0; mm < 2; mm++) {
          int mt = c * 2 + mm;
          ushort4 pk;
          pk.x = f2bf(pv2[nt][mt][0]); pk.y = f2bf(pv2[nt][mt][1]);
          pk.z = f2bf(pv2[nt][mt][2]); pk.w = f2bf(pv2[nt][mt][3]);
          *(ushort4*)(Pw + (nt * 16 + fr) * 80 + mm * 32 + quad * 8) = pk;
        }
      bf16x8_t ap0 = *(const bf16x8_t*)(Pw + fr * 80 + quad * 16);
      bf16x8_t ap1 = *(const bf16x8_t*)(Pw + (16 + fr) * 80 + quad * 16);
#pragma unroll
      for (int nd = 0; nd < 4; nd++) {
        bf16x8_t bv = *(const bf16x8_t*)(Vc + (size_t)(nd * 16 + fr) * 1024
                                         + (((sb + c * 32) * 2 + quad * 16) ^ kxor));
        O[0][nd] = __builtin_amdgcn_mfma_f32_16x16x32_bf16(ap0, bv, O[0][nd], 0, 0, 0);
        O[1][nd] = __builtin_amdgcn_mfma_f32_16x16x32_bf16(ap1, bv, O[1][nd], 0, 0, 0);
      }
    }
  }

  // ---- epilogue: O / l * nm ----
#pragma unroll
  for (int mp = 0; mp < 2; mp++) {
    const int p0 = wave * 32 + mp * 16 + quad * 4;
#pragma unroll
    for (int r = 0; r < 4; r++) {
      float lb = __shfl(l_run[mp], quad * 4 + r, 64);
      float nm = nmask[b * 256 + p0 + r];
      float scl = nm / lb;
#pragma unroll
      for (int nd = 0; nd < 4; nd++)
        outA[(size_t)(b * 256 + p0 + r) * 768 + h * 64 + nd * 16 + fr] = O[mp][nd][r] * scl;
    }
  }
}

extern "C" void kernel_launch(void* const* d_in, const int* in_sizes, int n_in,
                              void* d_out, int out_size, void* d_ws, size_t ws_size,
                              hipStream_t stream) {
  const float* hs   = (const float*)d_in[0];
  const int*   mask = (const int*)d_in[1];
  const float* W    = (const float*)d_in[2];
  const float* bias = (const float*)d_in[3];
  float* out = (float*)d_out;
  char* ws = (char*)d_ws;
  // ws layout (bytes) — FIXED round-6 overlap (Kbuf is 50331648 B, not 49152000):
  //   A    [0,         50331648)   32768x768 bf16
  //   Wt   [50331648,  53870592)   2304x768 bf16
  //   Kbuf [53870592,  104202240)  32768x768 bf16
  //   Vbuf [104202240, 154533888)  32768x768 bf16
  //   Ap   [154533888, 179699712)  16384x768 bf16 (pooled hidden)
  //   qp   [179699712, 204865536)  16384x768 bf16 (pooled q * 1/8)
  ushort* A    = (ushort*)(ws);
  ushort* Wt   = (ushort*)(ws + 50331648);
  ushort* Kbuf = (ushort*)(ws + 53870592);
  ushort* Vbuf = (ushort*)(ws + 104202240);
  ushort* Ap   = (ushort*)(ws + 154533888);
  ushort* qp   = (ushort*)(ws + 179699712);
  float* nmask = out + 12582912;
  float* resid = out + 12599296;

  hipLaunchKernelGGL(prep_kernel, dim3(9920), dim3(256), 0, stream,
                     hs, mask, A, Ap, W, Wt, nmask);
  hipLaunchKernelGGL(gemm_qkv_kernel, dim3(960), dim3(512), 0, stream,
                     A, Ap, Wt, bias, mask, nmask, Kbuf, Vbuf, resid, qp);
  hipLaunchKernelGGL(attn_kernel, dim3(12, 64), dim3(512), 0, stream,
                     Kbuf, Vbuf, qp, mask, nmask, out);
}